// Round 1
// baseline (422.907 us; speedup 1.0000x reference)
//
#include <hip/hip_runtime.h>

// ---------------------------------------------------------------------------
// QGaloreLinear: y[b,s,o] = sum_i x[b,s,i] * (qw[o,i]-zeros[g])*scales[g] + bias[o]
//   M = B*S = 8192, N = OUT = 4096, K = IN = 4096, GROUP = 256 (g = (o*K+i)/256)
// Strategy: dequant W -> bf16 (ws), convert x -> bf16 (ws), bf16 MFMA GEMM
// (m97 128x128-tile structure, global_load_lds width-16 staging, fp32 accum).
// ---------------------------------------------------------------------------

typedef __attribute__((ext_vector_type(8))) short bf16x8;     // 8 bf16 = 4 VGPRs
typedef __attribute__((ext_vector_type(8))) unsigned short ushort8;
typedef __attribute__((ext_vector_type(4))) float f32x4;

__device__ inline unsigned short f2bf(float f) {
  union { float f; unsigned int u; } v; v.f = f;
  unsigned int u = v.u;
  // round-to-nearest-even bf16
  return (unsigned short)((u + 0x7fffu + ((u >> 16) & 1u)) >> 16);
}

// ---- kernel 1: dequantize int32 qweight -> bf16 Wb[N][K] --------------------
__global__ void dequant_w_kernel(const int* __restrict__ q,
                                 const float* __restrict__ sc,
                                 const float* __restrict__ zp,
                                 ushort8* __restrict__ wb, int total8) {
  int t = blockIdx.x * blockDim.x + threadIdx.x;
  if (t >= total8) return;
  const int4* q4 = (const int4*)q + (size_t)t * 2;
  int4 a = q4[0];
  int4 b = q4[1];
  int g = t >> 5;               // (t*8)/256: 32 chunks of 8 per group
  float s = sc[g], z = zp[g];
  ushort8 o;
  o[0] = f2bf(((float)a.x - z) * s);
  o[1] = f2bf(((float)a.y - z) * s);
  o[2] = f2bf(((float)a.z - z) * s);
  o[3] = f2bf(((float)a.w - z) * s);
  o[4] = f2bf(((float)b.x - z) * s);
  o[5] = f2bf(((float)b.y - z) * s);
  o[6] = f2bf(((float)b.z - z) * s);
  o[7] = f2bf(((float)b.w - z) * s);
  wb[t] = o;
}

// ---- kernel 2: convert fp32 x -> bf16 Xb[M][K] ------------------------------
__global__ void convert_x_kernel(const float* __restrict__ x,
                                 ushort8* __restrict__ xb, int total8) {
  int t = blockIdx.x * blockDim.x + threadIdx.x;
  if (t >= total8) return;
  const float4* x4 = (const float4*)x + (size_t)t * 2;
  float4 a = x4[0];
  float4 b = x4[1];
  ushort8 o;
  o[0] = f2bf(a.x); o[1] = f2bf(a.y); o[2] = f2bf(a.z); o[3] = f2bf(a.w);
  o[4] = f2bf(b.x); o[5] = f2bf(b.y); o[6] = f2bf(b.z); o[7] = f2bf(b.w);
  xb[t] = o;
}

// ---- kernel 3: bf16 GEMM  C[M][N] = Xb[M][K] * Wb[N][K]^T + bias ------------
#define BM 128
#define BN 128
#define BK 64

__device__ inline void gload_lds16(const void* g, void* l) {
  __builtin_amdgcn_global_load_lds(
      (const __attribute__((address_space(1))) unsigned int*)g,
      (__attribute__((address_space(3))) unsigned int*)l, 16, 0, 0);
}

__global__ __launch_bounds__(256)
void gemm_bt_kernel(const unsigned short* __restrict__ A,  // Xb, M x K bf16
                    const unsigned short* __restrict__ B,  // Wb, N x K bf16
                    const float* __restrict__ bias,
                    float* __restrict__ C,
                    int M, int N, int K) {
  __shared__ short sA[BM * BK];   // [128][64] bf16, 16 KiB
  __shared__ short sB[BN * BK];

  const int t    = threadIdx.x;
  const int lane = t & 63;
  const int wave = t >> 6;
  const int wr   = wave >> 1;           // wave row  (0..1) -> 64 rows
  const int wc   = wave & 1;            // wave col  (0..1) -> 64 cols
  const int row0 = blockIdx.y * BM;
  const int col0 = blockIdx.x * BN;

  const int lr = lane & 15;             // fragment row
  const int lk = (lane >> 4) * 8;       // fragment k-offset
  const int lq = (lane >> 4) * 4;       // C fragment row group

  f32x4 acc[4][4] = {};

  // staging geometry: tile = 1024 chunks of 16B; 256 thr x 4 insts
  // chunk c -> row = c>>3, colbyte = (c&7)*16 ; LDS linear at c*16
  const int c_t = t;                     // chunk base per inst: inst*256 + t
  const char* gAbase = (const char*)A + ((size_t)row0 * K) * 2;
  const char* gBbase = (const char*)B + ((size_t)col0 * K) * 2;

  for (int k0 = 0; k0 < K; k0 += BK) {
#pragma unroll
    for (int inst = 0; inst < 4; ++inst) {
      const int c    = inst * 256 + c_t;
      const int r    = c >> 3;
      const int colb = (c & 7) * 16;
      const size_t goff = (size_t)r * K * 2 + (size_t)k0 * 2 + colb;
      // wave-uniform LDS base: hardware scatters lane i at base + i*16
      char* lA = (char*)sA + (size_t)(inst * 256 + wave * 64) * 16;
      char* lB = (char*)sB + (size_t)(inst * 256 + wave * 64) * 16;
      gload_lds16(gAbase + goff, lA);
      gload_lds16(gBbase + goff, lB);
    }
    __syncthreads();

#pragma unroll
    for (int kk = 0; kk < BK; kk += 32) {
      bf16x8 af[4], bfr[4];
#pragma unroll
      for (int m = 0; m < 4; ++m)
        af[m] = *(const bf16x8*)&sA[(wr * 64 + m * 16 + lr) * BK + kk + lk];
#pragma unroll
      for (int n = 0; n < 4; ++n)
        bfr[n] = *(const bf16x8*)&sB[(wc * 64 + n * 16 + lr) * BK + kk + lk];
#pragma unroll
      for (int m = 0; m < 4; ++m)
#pragma unroll
        for (int n = 0; n < 4; ++n)
          acc[m][n] = __builtin_amdgcn_mfma_f32_16x16x32_bf16(
              af[m], bfr[n], acc[m][n], 0, 0, 0);
    }
    __syncthreads();
  }

  // epilogue: C[row][col] = acc + bias[col]
#pragma unroll
  for (int n = 0; n < 4; ++n) {
    const int col = col0 + wc * 64 + n * 16 + lr;
    const float bv = bias[col];
#pragma unroll
    for (int m = 0; m < 4; ++m) {
      const int rbase = row0 + wr * 64 + m * 16 + lq;
#pragma unroll
      for (int j = 0; j < 4; ++j)
        C[(size_t)(rbase + j) * N + col] = acc[m][n][j] + bv;
    }
  }
}

// ---------------------------------------------------------------------------
extern "C" void kernel_launch(void* const* d_in, const int* in_sizes, int n_in,
                              void* d_out, int out_size, void* d_ws, size_t ws_size,
                              hipStream_t stream) {
  const float* x      = (const float*)d_in[0];
  const int*   qw     = (const int*)d_in[1];
  const float* scales = (const float*)d_in[2];
  const float* zeros  = (const float*)d_in[3];
  const float* bias   = (const float*)d_in[4];
  float* out = (float*)d_out;

  const int OUT = in_sizes[4];                 // 4096
  const int IN  = in_sizes[1] / OUT;           // 4096
  const int M   = in_sizes[0] / IN;            // 8192

  unsigned short* wb = (unsigned short*)d_ws;                    // OUT*IN bf16
  unsigned short* xb = wb + (size_t)OUT * IN;                    // M*IN  bf16

  {
    int total8 = OUT * IN / 8;
    dequant_w_kernel<<<(total8 + 255) / 256, 256, 0, stream>>>(
        qw, scales, zeros, (ushort8*)wb, total8);
  }
  {
    int total8 = (int)((size_t)M * IN / 8);
    convert_x_kernel<<<(total8 + 255) / 256, 256, 0, stream>>>(
        x, (ushort8*)xb, total8);
  }
  {
    dim3 grid(OUT / BN, M / BM);
    gemm_bt_kernel<<<grid, 256, 0, stream>>>(xb, wb, bias, out, M, OUT, IN);
  }
}

// Round 2
// 293.182 us; speedup vs baseline: 1.4425x; 1.4425x over previous
//
#include <hip/hip_runtime.h>

// ---------------------------------------------------------------------------
// QGaloreLinear: y = x @ dequant(qw)^T + bias.  M=8192, N=4096, K=4096.
// R2: 256x256-tile 8-phase bf16 MFMA GEMM (HK/m201 template in plain HIP):
//   T1 XCD-swizzle, T2 slot-XOR LDS swizzle (both-sides), T3+T4 8-phase with
//   counted vmcnt(6), T5 setprio around MFMA clusters. fp32 accumulate.
// ---------------------------------------------------------------------------

typedef __attribute__((ext_vector_type(8))) short bf16x8;
typedef __attribute__((ext_vector_type(8))) unsigned short ushort8;
typedef __attribute__((ext_vector_type(4))) float f32x4;

__device__ inline unsigned short f2bf(float f) {
  union { float f; unsigned int u; } v; v.f = f;
  unsigned int u = v.u;
  return (unsigned short)((u + 0x7fffu + ((u >> 16) & 1u)) >> 16);
}

// ---- kernel 1: dequantize int32 qweight -> bf16 Wb[N][K] --------------------
__global__ void dequant_w_kernel(const int* __restrict__ q,
                                 const float* __restrict__ sc,
                                 const float* __restrict__ zp,
                                 ushort8* __restrict__ wb, int total8) {
  int t = blockIdx.x * blockDim.x + threadIdx.x;
  if (t >= total8) return;
  const int4* q4 = (const int4*)q + (size_t)t * 2;
  int4 a = q4[0];
  int4 b = q4[1];
  int g = t >> 5;               // (t*8)/256
  float s = sc[g], z = zp[g];
  ushort8 o;
  o[0] = f2bf(((float)a.x - z) * s);
  o[1] = f2bf(((float)a.y - z) * s);
  o[2] = f2bf(((float)a.z - z) * s);
  o[3] = f2bf(((float)a.w - z) * s);
  o[4] = f2bf(((float)b.x - z) * s);
  o[5] = f2bf(((float)b.y - z) * s);
  o[6] = f2bf(((float)b.z - z) * s);
  o[7] = f2bf(((float)b.w - z) * s);
  wb[t] = o;
}

// ---- kernel 2: convert fp32 x -> bf16 Xb[M][K] ------------------------------
__global__ void convert_x_kernel(const float* __restrict__ x,
                                 ushort8* __restrict__ xb, int total8) {
  int t = blockIdx.x * blockDim.x + threadIdx.x;
  if (t >= total8) return;
  const float4* x4 = (const float4*)x + (size_t)t * 2;
  float4 a = x4[0];
  float4 b = x4[1];
  ushort8 o;
  o[0] = f2bf(a.x); o[1] = f2bf(a.y); o[2] = f2bf(a.z); o[3] = f2bf(a.w);
  o[4] = f2bf(b.x); o[5] = f2bf(b.y); o[6] = f2bf(b.z); o[7] = f2bf(b.w);
  xb[t] = o;
}

// ---- kernel 3: 256x256 8-phase bf16 GEMM ------------------------------------
#define BM 256
#define BN 256
#define BK 64

#define BAR()       asm volatile("s_barrier" ::: "memory")
#define WAIT_LGKM0() asm volatile("s_waitcnt lgkmcnt(0)" ::: "memory")
#define MFMA_(d, x, y) d = __builtin_amdgcn_mfma_f32_16x16x32_bf16(x, y, d, 0, 0, 0)

__device__ inline void gload_lds16(const void* g, void* l) {
  __builtin_amdgcn_global_load_lds(
      (const __attribute__((address_space(1))) unsigned int*)g,
      (__attribute__((address_space(3))) unsigned int*)l, 16, 0, 0);
}

// Stage one 128-row x 64-col bf16 half-tile (16 KiB) with pre-swizzled global
// source so that LDS slot q of row r holds global 16B-slot (q ^ (r&7)).
// LDS dest is linear (wave-uniform base + lane*16), per m104/m173.
__device__ inline void stage_half(const unsigned short* __restrict__ gsrc,
                                  char* lds_region, int K, int wave, int lane) {
  const int l3  = lane >> 3;                    // row low bits
  const int swz = ((lane & 7) ^ l3) * 8;        // swizzled 16B slot, in elems
#pragma unroll
  for (int inst = 0; inst < 2; ++inst) {
    const int row = inst * 64 + wave * 8 + l3;  // 0..127
    gload_lds16(gsrc + (size_t)row * K + swz,
                lds_region + (size_t)(inst * 512 + wave * 64) * 16);
  }
}

__global__ __launch_bounds__(512, 2)
void gemm256_kernel(const unsigned short* __restrict__ A,  // Xb, M x K
                    const unsigned short* __restrict__ B,  // Wb, N x K
                    const float* __restrict__ bias,
                    float* __restrict__ C,
                    int M, int N, int K) {
  extern __shared__ char lds[];   // 2 bufs x (A 32K + B 32K) = 128 KiB
  const int t    = threadIdx.x;
  const int lane = t & 63;
  const int wave = t >> 6;
  const int wm   = wave >> 2;          // 0..1  -> 128 output rows
  const int wn   = wave & 3;           // 0..3  -> 64 output cols
  const int lr   = lane & 15;
  const int hi   = lane >> 4;          // 0..3
  const int l7   = lane & 7;

  // T1: bijective XCD swizzle (nwg % 8 == 0 here: 512)
  const int nwg = gridDim.x;
  const int cpx = nwg >> 3;
  const int bid = blockIdx.x;
  const int swzb = (bid & 7) * cpx + (bid >> 3);
  const int ntn = N / BN;
  const int bm = swzb / ntn, bn = swzb % ntn;
  const int row0 = bm * BM, col0 = bn * BN;

  const int NT = K / BK;

  // swizzled ds_read byte offsets for the two K=32 sub-steps
  const int soff0 = (((0) + hi) ^ l7) * 16;    // kk=0  : slot 0..3
  const int soff1 = (((4) + hi) ^ l7) * 16;    // kk=32 : slot 4..7

  const unsigned short* Asrc = A + (size_t)row0 * K;
  const unsigned short* Bsrc = B + (size_t)col0 * K;

#define STAGE_B0(buf, kt) stage_half(Bsrc + (size_t)(kt) * BK,               (buf) + 32768,         K, wave, lane)
#define STAGE_B1(buf, kt) stage_half(Bsrc + (size_t)128 * K + (kt) * BK,     (buf) + 32768 + 16384, K, wave, lane)
#define STAGE_A0(buf, kt) stage_half(Asrc + (size_t)(kt) * BK,               (buf),                 K, wave, lane)
#define STAGE_A1(buf, kt) stage_half(Asrc + (size_t)128 * K + (kt) * BK,     (buf) + 16384,         K, wave, lane)

  f32x4 acc[8][4] = {};
  bf16x8 a[4][2], b[4][2];

  // ---- prologue: kt0 full (B0,B1,A0,A1) + kt1 (B0,B1,A0) ----
  char* buf0 = lds;
  char* buf1 = lds + 65536;
  STAGE_B0(buf0, 0); STAGE_B1(buf0, 0); STAGE_A0(buf0, 0); STAGE_A1(buf0, 0);
  asm volatile("s_waitcnt vmcnt(4)" ::: "memory");
  STAGE_B0(buf1, 1); STAGE_B1(buf1, 1); STAGE_A0(buf1, 1);
  asm volatile("s_waitcnt vmcnt(6)" ::: "memory");
  BAR();

  for (int kt = 0; kt < NT; ++kt) {
    char* buf  = lds + ((size_t)(kt & 1) << 16);
    char* nbuf = lds + ((size_t)((kt & 1) ^ 1) << 16);
    const char* Ab = buf;
    const char* Bb = buf + 32768;

    // ===== phase 0: read A(mh0) 8x + B(n0,n1) 4x ; stage next-kt A1 =====
#pragma unroll
    for (int mm = 0; mm < 4; ++mm) {
      const int r = (wm * 128 + mm * 16 + lr) * 128;
      a[mm][0] = *(const bf16x8*)(Ab + r + soff0);
      a[mm][1] = *(const bf16x8*)(Ab + r + soff1);
    }
#pragma unroll
    for (int n = 0; n < 2; ++n) {
      const int r = (wn * 64 + n * 16 + lr) * 128;
      b[n][0] = *(const bf16x8*)(Bb + r + soff0);
      b[n][1] = *(const bf16x8*)(Bb + r + soff1);
    }
    if (kt + 1 < NT) STAGE_A1(nbuf, kt + 1);
    asm volatile("s_waitcnt lgkmcnt(8)" ::: "memory");
    BAR();
    WAIT_LGKM0();
    __builtin_amdgcn_s_setprio(1);
#pragma unroll
    for (int mm = 0; mm < 4; ++mm)
#pragma unroll
      for (int n = 0; n < 2; ++n) {
        MFMA_(acc[mm][n], a[mm][0], b[n][0]);
        MFMA_(acc[mm][n], a[mm][1], b[n][1]);
      }
    __builtin_amdgcn_s_setprio(0);
    BAR();

    // ===== phase 1: read B(n2,n3) 4x ; stage kt+2 B0 (this buffer) =====
#pragma unroll
    for (int n = 2; n < 4; ++n) {
      const int r = (wn * 64 + n * 16 + lr) * 128;
      b[n][0] = *(const bf16x8*)(Bb + r + soff0);
      b[n][1] = *(const bf16x8*)(Bb + r + soff1);
    }
    if (kt + 2 < NT) STAGE_B0(buf, kt + 2);
    BAR();
    WAIT_LGKM0();
    __builtin_amdgcn_s_setprio(1);
#pragma unroll
    for (int mm = 0; mm < 4; ++mm)
#pragma unroll
      for (int n = 2; n < 4; ++n) {
        MFMA_(acc[mm][n], a[mm][0], b[n][0]);
        MFMA_(acc[mm][n], a[mm][1], b[n][1]);
      }
    __builtin_amdgcn_s_setprio(0);
    BAR();

    // ===== phase 2: read A(mh1) 8x ; stage kt+2 B1 =====
#pragma unroll
    for (int mm = 0; mm < 4; ++mm) {
      const int r = (wm * 128 + 64 + mm * 16 + lr) * 128;
      a[mm][0] = *(const bf16x8*)(Ab + r + soff0);
      a[mm][1] = *(const bf16x8*)(Ab + r + soff1);
    }
    if (kt + 2 < NT) STAGE_B1(buf, kt + 2);
    BAR();
    WAIT_LGKM0();
    __builtin_amdgcn_s_setprio(1);
#pragma unroll
    for (int mm = 0; mm < 4; ++mm)
#pragma unroll
      for (int n = 0; n < 2; ++n) {
        MFMA_(acc[4 + mm][n], a[mm][0], b[n][0]);
        MFMA_(acc[4 + mm][n], a[mm][1], b[n][1]);
      }
    __builtin_amdgcn_s_setprio(0);
    BAR();

    // ===== phase 3: no reads ; stage kt+2 A0 ; counted vmcnt =====
    if (kt + 2 < NT) STAGE_A0(buf, kt + 2);
    BAR();
    __builtin_amdgcn_s_setprio(1);
#pragma unroll
    for (int mm = 0; mm < 4; ++mm)
#pragma unroll
      for (int n = 2; n < 4; ++n) {
        MFMA_(acc[4 + mm][n], a[mm][0], b[n][0]);
        MFMA_(acc[4 + mm][n], a[mm][1], b[n][1]);
      }
    __builtin_amdgcn_s_setprio(0);
    if (kt < NT - 2)      asm volatile("s_waitcnt vmcnt(6)" ::: "memory");
    else if (kt == NT - 2) asm volatile("s_waitcnt vmcnt(0)" ::: "memory");
    BAR();
  }

  // ---- epilogue: C = acc + bias ----
#pragma unroll
  for (int n = 0; n < 4; ++n) {
    const int col = col0 + wn * 64 + n * 16 + lr;
    const float bv = bias[col];
#pragma unroll
    for (int m = 0; m < 8; ++m) {
      const int rbase = row0 + wm * 128 + m * 16 + hi * 4;
#pragma unroll
      for (int j = 0; j < 4; ++j)
        C[(size_t)(rbase + j) * N + col] = acc[m][n][j] + bv;
    }
  }
#undef STAGE_B0
#undef STAGE_B1
#undef STAGE_A0
#undef STAGE_A1
}

// ---------------------------------------------------------------------------
extern "C" void kernel_launch(void* const* d_in, const int* in_sizes, int n_in,
                              void* d_out, int out_size, void* d_ws, size_t ws_size,
                              hipStream_t stream) {
  const float* x      = (const float*)d_in[0];
  const int*   qw     = (const int*)d_in[1];
  const float* scales = (const float*)d_in[2];
  const float* zeros  = (const float*)d_in[3];
  const float* bias   = (const float*)d_in[4];
  float* out = (float*)d_out;

  const int OUT = in_sizes[4];                 // 4096
  const int IN  = in_sizes[1] / OUT;           // 4096
  const int M   = in_sizes[0] / IN;            // 8192

  unsigned short* wb = (unsigned short*)d_ws;                 // OUT*IN bf16
  unsigned short* xb = wb + (size_t)OUT * IN;                 // M*IN  bf16

  {
    int total8 = OUT * IN / 8;
    dequant_w_kernel<<<(total8 + 255) / 256, 256, 0, stream>>>(
        qw, scales, zeros, (ushort8*)wb, total8);
  }
  {
    int total8 = (int)((size_t)M * IN / 8);
    convert_x_kernel<<<(total8 + 255) / 256, 256, 0, stream>>>(
        x, (ushort8*)xb, total8);
  }
  {
    hipFuncSetAttribute((const void*)gemm256_kernel,
                        hipFuncAttributeMaxDynamicSharedMemorySize, 131072);
    dim3 grid((M / BM) * (OUT / BN));
    gemm256_kernel<<<grid, 512, 131072, stream>>>(xb, wb, bias, out, M, OUT, IN);
  }
}